// Round 1
// baseline (1172.324 us; speedup 1.0000x reference)
//
#include <hip/hip_runtime.h>

// ---------------------------------------------------------------------------
// DualGNN: 2x (3-layer GCN encoder + mean-pool) + MLP head. All f32.
// Strategy: build dst-CSR per call (deg -> scan -> fill), then per layer:
//   gemm_scaled: hB = (h .* nsrc) @ W        (tiled vector-f32 GEMM)
//   agg:         hA[n] = relu(ndst[n]*sum_{e:dst=n} hB[src[e]] + b)
// pool: run-flush over sorted gid; MLP: one block per graph.
// ---------------------------------------------------------------------------

#define DHID 128

static __device__ __forceinline__ void fma4(float4& o, float a, const float4& w) {
  o.x = fmaf(a, w.x, o.x);
  o.y = fmaf(a, w.y, o.y);
  o.z = fmaf(a, w.z, o.z);
  o.w = fmaf(a, w.w, o.w);
}

// ---- degree histogram (int atomics) ---------------------------------------
__global__ void deg_kernel(const int* __restrict__ src, const int* __restrict__ dst,
                           int* __restrict__ deg_out, int* __restrict__ deg_in, int E) {
  int e = blockIdx.x * blockDim.x + threadIdx.x;
  if (e < E) {
    atomicAdd(&deg_out[src[e]], 1);
    atomicAdd(&deg_in[dst[e]], 1);
  }
}

// ---- norm = clip(deg,1)^-1/2 ----------------------------------------------
__global__ void norm_kernel(const int* __restrict__ deg_out, const int* __restrict__ deg_in,
                            float* __restrict__ nsrc, float* __restrict__ ndst, int N) {
  int i = blockIdx.x * blockDim.x + threadIdx.x;
  if (i < N) {
    nsrc[i] = 1.0f / sqrtf((float)max(deg_out[i], 1));
    ndst[i] = 1.0f / sqrtf((float)max(deg_in[i], 1));
  }
}

// ---- exclusive scan of deg_in -> rowptr (single block, 1024 thr) ----------
__global__ void scan_kernel(const int* __restrict__ deg, int* __restrict__ rowptr, int n) {
  __shared__ int wsum[16];
  __shared__ int carry_s;
  const int tid = threadIdx.x;
  const int lane = tid & 63;
  const int wv = tid >> 6;
  if (tid == 0) carry_s = 0;
  __syncthreads();
  for (int base = 0; base < n; base += 1024) {
    int i = base + tid;
    int v = (i < n) ? deg[i] : 0;
    int x = v;
    #pragma unroll
    for (int d = 1; d < 64; d <<= 1) {
      int y = __shfl_up(x, d);
      if (lane >= d) x += y;
    }
    if (lane == 63) wsum[wv] = x;
    __syncthreads();
    int woff = 0;
    for (int k = 0; k < wv; ++k) woff += wsum[k];
    int excl = carry_s + woff + x - v;
    if (i < n) rowptr[i] = excl;
    int total_local = woff + x;  // valid for tid==1023
    __syncthreads();
    if (tid == 1023) carry_s += total_local;
    __syncthreads();
  }
  if (tid == 0) rowptr[n] = carry_s;
}

// ---- CSR fill: colidx[slot(dst)] = src ------------------------------------
__global__ void fill_kernel(const int* __restrict__ src, const int* __restrict__ dst,
                            const int* __restrict__ rowptr, int* __restrict__ fill,
                            int* __restrict__ colidx, int E) {
  int e = blockIdx.x * blockDim.x + threadIdx.x;
  if (e < E) {
    int d = dst[e];
    int pos = rowptr[d] + atomicAdd(&fill[d], 1);
    colidx[pos] = src[e];
  }
}

// ---- tiled GEMM: out[n][c] = nsrc[n] * sum_k A[n][k]*W[k][c], C=128 -------
#define BM 128
#define BKC 32
__global__ __launch_bounds__(256) void gemm_scaled(
    const float* __restrict__ A, const float* __restrict__ W,
    const float* __restrict__ nsrc, float* __restrict__ out,
    int nrows, int K) {
  __shared__ __align__(16) float As[BM][BKC + 4];   // +4 pad: row stride 36 floats (16B aligned)
  __shared__ __align__(16) float Ws[BKC][DHID];
  const int tid = threadIdx.x;
  const int row0 = blockIdx.x * BM;
  const int cx = tid & 15;   // cols cx*4..+3 and 64+cx*4..+3
  const int ry = tid >> 4;   // rows ry + 16*r, r=0..7  (strided: bank-spread broadcasts)
  const int lr = tid >> 1;         // A-load row 0..127
  const int lk = (tid & 1) * 16;   // A-load k offset
  const int wk = tid >> 3;         // W-load row 0..31
  const int wc = (tid & 7) * 4;    // W-load col

  float4 acc[8][2];
  #pragma unroll
  for (int r = 0; r < 8; ++r) {
    acc[r][0] = make_float4(0.f, 0.f, 0.f, 0.f);
    acc[r][1] = make_float4(0.f, 0.f, 0.f, 0.f);
  }

  const int arow = row0 + lr;
  const float scale = (arow < nrows) ? nsrc[arow] : 0.f;

  for (int k0 = 0; k0 < K; k0 += BKC) {
    if (arow < nrows) {
      const float4* ap = (const float4*)(A + (size_t)arow * K + k0 + lk);
      #pragma unroll
      for (int j = 0; j < 4; ++j) {
        float4 v = ap[j];
        v.x *= scale; v.y *= scale; v.z *= scale; v.w *= scale;
        *(float4*)&As[lr][lk + j * 4] = v;
      }
    } else {
      #pragma unroll
      for (int j = 0; j < 4; ++j)
        *(float4*)&As[lr][lk + j * 4] = make_float4(0.f, 0.f, 0.f, 0.f);
    }
    {
      const float* wp = W + (size_t)(k0 + wk) * DHID;
      #pragma unroll
      for (int j = 0; j < 4; ++j)
        *(float4*)&Ws[wk][wc + j * 32] = *(const float4*)(wp + wc + j * 32);
    }
    __syncthreads();
    #pragma unroll 4
    for (int kk = 0; kk < BKC; kk += 2) {
      float4 w00 = *(float4*)&Ws[kk][cx * 4];
      float4 w01 = *(float4*)&Ws[kk][64 + cx * 4];
      float4 w10 = *(float4*)&Ws[kk + 1][cx * 4];
      float4 w11 = *(float4*)&Ws[kk + 1][64 + cx * 4];
      #pragma unroll
      for (int r = 0; r < 8; ++r) {
        float2 a = *(float2*)&As[ry + 16 * r][kk];
        fma4(acc[r][0], a.x, w00);
        fma4(acc[r][1], a.x, w01);
        fma4(acc[r][0], a.y, w10);
        fma4(acc[r][1], a.y, w11);
      }
    }
    __syncthreads();
  }
  #pragma unroll
  for (int r = 0; r < 8; ++r) {
    int row = row0 + ry + 16 * r;
    if (row < nrows) {
      float* op = out + (size_t)row * DHID;
      *(float4*)(op + cx * 4) = acc[r][0];
      *(float4*)(op + 64 + cx * 4) = acc[r][1];
    }
  }
}

// ---- aggregation: one wave per dst node, fused ndst/bias/relu -------------
__global__ void agg_kernel(const float* __restrict__ hB, const int* __restrict__ rowptr,
                           const int* __restrict__ colidx, const float* __restrict__ ndst,
                           const float* __restrict__ bias, float* __restrict__ out, int N) {
  int wid = (blockIdx.x * blockDim.x + threadIdx.x) >> 6;
  int lane = threadIdx.x & 63;
  if (wid >= N) return;
  int beg = rowptr[wid];
  int end = rowptr[wid + 1];
  float2 acc = make_float2(0.f, 0.f);
  for (int j = beg; j < end; ++j) {
    int s = colidx[j];
    const float2 v = *(const float2*)(hB + (size_t)s * DHID + lane * 2);
    acc.x += v.x;
    acc.y += v.y;
  }
  float nd = ndst[wid];
  float2 b2 = *(const float2*)(bias + lane * 2);
  float2 o;
  o.x = fmaxf(fmaf(acc.x, nd, b2.x), 0.f);
  o.y = fmaxf(fmaf(acc.y, nd, b2.y), 0.f);
  *(float2*)(out + (size_t)wid * DHID + lane * 2) = o;
}

// ---- per-graph node counts ------------------------------------------------
__global__ void cnt_kernel(const int* __restrict__ gid, int* __restrict__ cnt, int N) {
  int i = blockIdx.x * blockDim.x + threadIdx.x;
  if (i < N) atomicAdd(&cnt[gid[i]], 1);
}

// ---- mean-pool numerator: run-flush over sorted gid -----------------------
__global__ void pool_kernel(const float* __restrict__ h, const int* __restrict__ gid,
                            float* __restrict__ pooled, int N, int C) {
  int wid = (blockIdx.x * blockDim.x + threadIdx.x) >> 6;
  int lane = threadIdx.x & 63;
  int n0 = wid * C;
  if (n0 >= N) return;
  int n1 = min(n0 + C, N);
  int gcur = gid[n0];
  float2 acc = make_float2(0.f, 0.f);
  for (int nd = n0; nd < n1; ++nd) {
    int g = gid[nd];
    if (g != gcur) {
      atomicAdd(&pooled[(size_t)gcur * DHID + lane * 2], acc.x);
      atomicAdd(&pooled[(size_t)gcur * DHID + lane * 2 + 1], acc.y);
      acc = make_float2(0.f, 0.f);
      gcur = g;
    }
    const float2 v = *(const float2*)(h + (size_t)nd * DHID + lane * 2);
    acc.x += v.x;
    acc.y += v.y;
  }
  atomicAdd(&pooled[(size_t)gcur * DHID + lane * 2], acc.x);
  atomicAdd(&pooled[(size_t)gcur * DHID + lane * 2 + 1], acc.y);
}

// ---- MLP head: one block (128 thr) per graph ------------------------------
__global__ void mlp_kernel(const float* __restrict__ psu, const float* __restrict__ psv,
                           const int* __restrict__ cnt_su, const int* __restrict__ cnt_sv,
                           const float* __restrict__ gf,
                           const float* __restrict__ W0, const float* __restrict__ b0,
                           const float* __restrict__ W1, const float* __restrict__ b1,
                           const float* __restrict__ W2, const float* __restrict__ b2,
                           float* __restrict__ out) {
  int g = blockIdx.x;
  int t = threadIdx.x;  // 128 threads
  __shared__ float comb[260];
  __shared__ float h0[128];
  __shared__ float h1[64];
  float inv_su = 1.0f / (float)max(cnt_su[g], 1);
  float inv_sv = 1.0f / (float)max(cnt_sv[g], 1);
  comb[t] = psu[(size_t)g * DHID + t] * inv_su;
  comb[128 + t] = psv[(size_t)g * DHID + t] * inv_sv;
  if (t < 4) comb[256 + t] = gf[g * 4 + t];
  __syncthreads();
  float acc = b0[t];
  for (int k = 0; k < 260; ++k) acc = fmaf(comb[k], W0[k * 128 + t], acc);
  h0[t] = fmaxf(acc, 0.f);
  __syncthreads();
  if (t < 64) {
    float a = b1[t];
    for (int k = 0; k < 128; ++k) a = fmaf(h0[k], W1[k * 64 + t], a);
    h1[t] = fmaxf(a, 0.f);
  }
  __syncthreads();
  if (t < 64) {
    float p = h1[t] * W2[t];
    #pragma unroll
    for (int d = 32; d > 0; d >>= 1) p += __shfl_down(p, d);
    if (t == 0) out[g] = p + b2[0];
  }
}

// ---------------------------------------------------------------------------
extern "C" void kernel_launch(void* const* d_in, const int* in_sizes, int n_in,
                              void* d_out, int out_size, void* d_ws, size_t ws_size,
                              hipStream_t stream) {
  const float* solute_x  = (const float*)d_in[0];
  const float* solvent_x = (const float*)d_in[1];
  const float* gfeat     = (const float*)d_in[2];
  const int* su_src = (const int*)d_in[3];
  const int* su_dst = (const int*)d_in[4];
  const int* sv_src = (const int*)d_in[5];
  const int* sv_dst = (const int*)d_in[6];
  const int* su_gid = (const int*)d_in[7];
  const int* sv_gid = (const int*)d_in[8];
  const float* enc_W[2][3] = {
    {(const float*)d_in[9],  (const float*)d_in[10], (const float*)d_in[11]},
    {(const float*)d_in[13], (const float*)d_in[14], (const float*)d_in[15]}};
  const float* enc_b[2] = {(const float*)d_in[12], (const float*)d_in[16]};
  const float* mW0 = (const float*)d_in[17];
  const float* mb0 = (const float*)d_in[18];
  const float* mW1 = (const float*)d_in[19];
  const float* mb1 = (const float*)d_in[20];
  const float* mW2 = (const float*)d_in[21];
  const float* mb2 = (const float*)d_in[22];

  const int N = in_sizes[0] / 64;   // 50000
  const int E = in_sizes[3];        // 800000
  const int G = in_sizes[2] / 4;    // 256

  const int* srcs[2] = {su_src, sv_src};
  const int* dsts[2] = {su_dst, sv_dst};
  const int* gids[2] = {su_gid, sv_gid};
  const float* xs[2] = {solute_x, solvent_x};

  // workspace carve-up (256B aligned)
  char* ws = (char*)d_ws;
  size_t off = 0;
  auto alloc = [&](size_t bytes) -> void* {
    void* p = ws + off;
    off = (off + bytes + 255) & ~(size_t)255;
    return p;
  };
  int*   ibase   = (int*)alloc((size_t)3 * N * 4);      // deg_out | deg_in | fill
  int*   deg_out = ibase;
  int*   deg_in  = ibase + N;
  int*   fill    = ibase + 2 * N;
  float* nsrc    = (float*)alloc((size_t)N * 4);
  float* ndst    = (float*)alloc((size_t)N * 4);
  int*   rowptr  = (int*)alloc((size_t)(N + 1) * 4);
  int*   colidx  = (int*)alloc((size_t)E * 4);
  float* bufA    = (float*)alloc((size_t)N * DHID * 4);
  float* bufB    = (float*)alloc((size_t)N * DHID * 4);
  float* pbase   = (float*)alloc(((size_t)2 * G * DHID + 2 * G) * 4); // pooled_su|pooled_sv|cnt_su|cnt_sv
  float* pooled_su = pbase;
  float* pooled_sv = pbase + (size_t)G * DHID;
  int*   cnt_su    = (int*)(pbase + (size_t)2 * G * DHID);
  int*   cnt_sv    = cnt_su + G;
  (void)ws_size; (void)n_in; (void)out_size;

  float* pooleds[2] = {pooled_su, pooled_sv};
  int*   cnts[2]    = {cnt_su, cnt_sv};

  hipMemsetAsync(pbase, 0, ((size_t)2 * G * DHID + 2 * G) * 4, stream);

  const int TB = 256;
  const int egrid = (E + TB - 1) / TB;
  const int ngrid = (N + TB - 1) / TB;
  const int ggrid = (N + BM - 1) / BM;
  const int agrid = (N + 3) / 4;               // 4 waves per 256-thr block, wave per node
  const int PC = 25;                           // nodes per wave in pool
  const int pwaves = (N + PC - 1) / PC;
  const int pgrid = (pwaves + 3) / 4;

  for (int enc = 0; enc < 2; ++enc) {
    hipMemsetAsync(ibase, 0, (size_t)3 * N * 4, stream);
    deg_kernel<<<egrid, TB, 0, stream>>>(srcs[enc], dsts[enc], deg_out, deg_in, E);
    norm_kernel<<<ngrid, TB, 0, stream>>>(deg_out, deg_in, nsrc, ndst, N);
    scan_kernel<<<1, 1024, 0, stream>>>(deg_in, rowptr, N);
    fill_kernel<<<egrid, TB, 0, stream>>>(srcs[enc], dsts[enc], rowptr, fill, colidx, E);

    const float* in = xs[enc];
    int K = 64;
    for (int l = 0; l < 3; ++l) {
      gemm_scaled<<<ggrid, TB, 0, stream>>>(in, enc_W[enc][l], nsrc, bufB, N, K);
      agg_kernel<<<agrid, TB, 0, stream>>>(bufB, rowptr, colidx, ndst,
                                           enc_b[enc] + l * DHID, bufA, N);
      in = bufA;
      K = DHID;
    }
    cnt_kernel<<<ngrid, TB, 0, stream>>>(gids[enc], cnts[enc], N);
    pool_kernel<<<pgrid, TB, 0, stream>>>(bufA, gids[enc], pooleds[enc], N, PC);
  }

  mlp_kernel<<<G, 128, 0, stream>>>(pooled_su, pooled_sv, cnt_su, cnt_sv, gfeat,
                                    mW0, mb0, mW1, mb1, mW2, mb2, (float*)d_out);
}

// Round 2
// 876.801 us; speedup vs baseline: 1.3370x; 1.3370x over previous
//
#include <hip/hip_runtime.h>

// ---------------------------------------------------------------------------
// DualGNN: 2x (3-layer GCN encoder + mean-pool) + MLP head. All f32.
//   CSR build: deg -> hierarchical scan (3 kernels, norm fused) -> fill
//   per layer: gemm_scaled (vector-f32 tiled GEMM), agg (wave/node gather,
//              shfl-broadcast colidx, float4 half-wave, 4x unroll for MLP)
// ---------------------------------------------------------------------------

#define DHID 128

static __device__ __forceinline__ void fma4(float4& o, float a, const float4& w) {
  o.x = fmaf(a, w.x, o.x);
  o.y = fmaf(a, w.y, o.y);
  o.z = fmaf(a, w.z, o.z);
  o.w = fmaf(a, w.w, o.w);
}
static __device__ __forceinline__ void add4(float4& o, const float4& v) {
  o.x += v.x; o.y += v.y; o.z += v.z; o.w += v.w;
}

// ---- degree histogram (int atomics) ---------------------------------------
__global__ void deg_kernel(const int* __restrict__ src, const int* __restrict__ dst,
                           int* __restrict__ deg_out, int* __restrict__ deg_in, int E) {
  int e = blockIdx.x * blockDim.x + threadIdx.x;
  if (e < E) {
    atomicAdd(&deg_out[src[e]], 1);
    atomicAdd(&deg_in[dst[e]], 1);
  }
}

// ---- scan pass 1: per-block sums of deg_in + fused norm computation -------
__global__ void scan_part(const int* __restrict__ deg_in, const int* __restrict__ deg_out,
                          int* __restrict__ part, float* __restrict__ nsrc,
                          float* __restrict__ ndst, int n) {
  const int tid = threadIdx.x;
  const int i = blockIdx.x * 256 + tid;
  int v = 0;
  if (i < n) {
    int di = deg_in[i];
    v = di;
    ndst[i] = 1.0f / sqrtf((float)max(di, 1));
    nsrc[i] = 1.0f / sqrtf((float)max(deg_out[i], 1));
  }
  #pragma unroll
  for (int d = 32; d > 0; d >>= 1) v += __shfl_xor(v, d);
  __shared__ int ws[4];
  if ((tid & 63) == 0) ws[tid >> 6] = v;
  __syncthreads();
  if (tid == 0) part[blockIdx.x] = ws[0] + ws[1] + ws[2] + ws[3];
}

// ---- scan pass 2: exclusive scan of partials (single block, nb<=256) ------
__global__ void scan_mid(int* __restrict__ part, int* __restrict__ total_out, int nb) {
  const int tid = threadIdx.x;
  const int lane = tid & 63;
  const int wv = tid >> 6;
  int v = (tid < nb) ? part[tid] : 0;
  int x = v;
  #pragma unroll
  for (int d = 1; d < 64; d <<= 1) {
    int y = __shfl_up(x, d);
    if (lane >= d) x += y;
  }
  __shared__ int ws[4];
  if (lane == 63) ws[wv] = x;
  __syncthreads();
  int woff = 0;
  for (int k = 0; k < wv; ++k) woff += ws[k];
  if (tid < nb) part[tid] = woff + x - v;
  if (tid == 255) *total_out = woff + x;  // grand total (v=0 past nb)
}

// ---- scan pass 3: block-local exclusive scan + block offset -> rowptr -----
__global__ void scan_final(const int* __restrict__ deg, const int* __restrict__ part,
                           int* __restrict__ rowptr, int n) {
  const int tid = threadIdx.x;
  const int i = blockIdx.x * 256 + tid;
  const int lane = tid & 63;
  const int wv = tid >> 6;
  int v = (i < n) ? deg[i] : 0;
  int x = v;
  #pragma unroll
  for (int d = 1; d < 64; d <<= 1) {
    int y = __shfl_up(x, d);
    if (lane >= d) x += y;
  }
  __shared__ int ws[4];
  if (lane == 63) ws[wv] = x;
  __syncthreads();
  int woff = 0;
  for (int k = 0; k < wv; ++k) woff += ws[k];
  if (i < n) rowptr[i] = part[blockIdx.x] + woff + x - v;
}

// ---- CSR fill: colidx[slot(dst)] = src ------------------------------------
__global__ void fill_kernel(const int* __restrict__ src, const int* __restrict__ dst,
                            const int* __restrict__ rowptr, int* __restrict__ fill,
                            int* __restrict__ colidx, int E) {
  int e = blockIdx.x * blockDim.x + threadIdx.x;
  if (e < E) {
    int d = dst[e];
    int pos = rowptr[d] + atomicAdd(&fill[d], 1);
    colidx[pos] = src[e];
  }
}

// ---- tiled GEMM: out[n][c] = nsrc[n] * sum_k A[n][k]*W[k][c], C=128 -------
#define BM 128
#define BKC 32
__global__ __launch_bounds__(256) void gemm_scaled(
    const float* __restrict__ A, const float* __restrict__ W,
    const float* __restrict__ nsrc, float* __restrict__ out,
    int nrows, int K) {
  __shared__ __align__(16) float As[BM][BKC + 4];
  __shared__ __align__(16) float Ws[BKC][DHID];
  const int tid = threadIdx.x;
  const int row0 = blockIdx.x * BM;
  const int cx = tid & 15;
  const int ry = tid >> 4;
  const int lr = tid >> 1;
  const int lk = (tid & 1) * 16;
  const int wk = tid >> 3;
  const int wc = (tid & 7) * 4;

  float4 acc[8][2];
  #pragma unroll
  for (int r = 0; r < 8; ++r) {
    acc[r][0] = make_float4(0.f, 0.f, 0.f, 0.f);
    acc[r][1] = make_float4(0.f, 0.f, 0.f, 0.f);
  }

  const int arow = row0 + lr;
  const float scale = (arow < nrows) ? nsrc[arow] : 0.f;

  for (int k0 = 0; k0 < K; k0 += BKC) {
    if (arow < nrows) {
      const float4* ap = (const float4*)(A + (size_t)arow * K + k0 + lk);
      #pragma unroll
      for (int j = 0; j < 4; ++j) {
        float4 v = ap[j];
        v.x *= scale; v.y *= scale; v.z *= scale; v.w *= scale;
        *(float4*)&As[lr][lk + j * 4] = v;
      }
    } else {
      #pragma unroll
      for (int j = 0; j < 4; ++j)
        *(float4*)&As[lr][lk + j * 4] = make_float4(0.f, 0.f, 0.f, 0.f);
    }
    {
      const float* wp = W + (size_t)(k0 + wk) * DHID;
      #pragma unroll
      for (int j = 0; j < 4; ++j)
        *(float4*)&Ws[wk][wc + j * 32] = *(const float4*)(wp + wc + j * 32);
    }
    __syncthreads();
    #pragma unroll 4
    for (int kk = 0; kk < BKC; kk += 2) {
      float4 w00 = *(float4*)&Ws[kk][cx * 4];
      float4 w01 = *(float4*)&Ws[kk][64 + cx * 4];
      float4 w10 = *(float4*)&Ws[kk + 1][cx * 4];
      float4 w11 = *(float4*)&Ws[kk + 1][64 + cx * 4];
      #pragma unroll
      for (int r = 0; r < 8; ++r) {
        float2 a = *(float2*)&As[ry + 16 * r][kk];
        fma4(acc[r][0], a.x, w00);
        fma4(acc[r][1], a.x, w01);
        fma4(acc[r][0], a.y, w10);
        fma4(acc[r][1], a.y, w11);
      }
    }
    __syncthreads();
  }
  #pragma unroll
  for (int r = 0; r < 8; ++r) {
    int row = row0 + ry + 16 * r;
    if (row < nrows) {
      float* op = out + (size_t)row * DHID;
      *(float4*)(op + cx * 4) = acc[r][0];
      *(float4*)(op + 64 + cx * 4) = acc[r][1];
    }
  }
}

// ---- aggregation v2: wave/node, shfl-broadcast colidx, float4 half-wave ---
// half 0 (lanes 0-31) and half 1 (lanes 32-63) each cover all 128 cols via
// float4, processing even/odd edges respectively; cross-half reduce at end.
__global__ void agg_kernel(const float* __restrict__ hB, const int* __restrict__ rowptr,
                           const int* __restrict__ colidx, const float* __restrict__ ndst,
                           const float* __restrict__ bias, float* __restrict__ out, int N) {
  int wid = (blockIdx.x * blockDim.x + threadIdx.x) >> 6;
  int lane = threadIdx.x & 63;
  if (wid >= N) return;
  int beg = rowptr[wid];
  int end = rowptr[wid + 1];
  const int half = lane >> 5;
  const int col = (lane & 31) * 4;
  float4 acc = make_float4(0.f, 0.f, 0.f, 0.f);

  for (int c0 = beg; c0 < end; c0 += 64) {
    int cnt = min(end - c0, 64);
    int myidx = (lane < cnt) ? colidx[c0 + lane] : 0;
    int pairs = cnt >> 1;
    int j = 0;
    // 4x unroll: issue 4 independent gathers before consuming (MLP=4)
    for (; j + 4 <= pairs; j += 4) {
      int s0 = __shfl(myidx, 2 * j + half);
      int s1 = __shfl(myidx, 2 * j + 2 + half);
      int s2 = __shfl(myidx, 2 * j + 4 + half);
      int s3 = __shfl(myidx, 2 * j + 6 + half);
      float4 v0 = *(const float4*)(hB + (size_t)s0 * DHID + col);
      float4 v1 = *(const float4*)(hB + (size_t)s1 * DHID + col);
      float4 v2 = *(const float4*)(hB + (size_t)s2 * DHID + col);
      float4 v3 = *(const float4*)(hB + (size_t)s3 * DHID + col);
      add4(acc, v0); add4(acc, v1); add4(acc, v2); add4(acc, v3);
    }
    for (; j < pairs; ++j) {
      int s = __shfl(myidx, 2 * j + half);
      float4 v = *(const float4*)(hB + (size_t)s * DHID + col);
      add4(acc, v);
    }
    if (cnt & 1) {
      int s = __shfl(myidx, cnt - 1);
      if (half == 0) {
        float4 v = *(const float4*)(hB + (size_t)s * DHID + col);
        add4(acc, v);
      }
    }
  }
  // cross-half reduce (same col lives at lane^32)
  acc.x += __shfl_xor(acc.x, 32);
  acc.y += __shfl_xor(acc.y, 32);
  acc.z += __shfl_xor(acc.z, 32);
  acc.w += __shfl_xor(acc.w, 32);
  if (half == 0) {
    float nd = ndst[wid];
    float4 b = *(const float4*)(bias + col);
    float4 o;
    o.x = fmaxf(fmaf(acc.x, nd, b.x), 0.f);
    o.y = fmaxf(fmaf(acc.y, nd, b.y), 0.f);
    o.z = fmaxf(fmaf(acc.z, nd, b.z), 0.f);
    o.w = fmaxf(fmaf(acc.w, nd, b.w), 0.f);
    *(float4*)(out + (size_t)wid * DHID + col) = o;
  }
}

// ---- per-graph node counts ------------------------------------------------
__global__ void cnt_kernel(const int* __restrict__ gid, int* __restrict__ cnt, int N) {
  int i = blockIdx.x * blockDim.x + threadIdx.x;
  if (i < N) atomicAdd(&cnt[gid[i]], 1);
}

// ---- mean-pool numerator: run-flush over sorted gid -----------------------
__global__ void pool_kernel(const float* __restrict__ h, const int* __restrict__ gid,
                            float* __restrict__ pooled, int N, int C) {
  int wid = (blockIdx.x * blockDim.x + threadIdx.x) >> 6;
  int lane = threadIdx.x & 63;
  int n0 = wid * C;
  if (n0 >= N) return;
  int n1 = min(n0 + C, N);
  int gcur = gid[n0];
  float2 acc = make_float2(0.f, 0.f);
  for (int nd = n0; nd < n1; ++nd) {
    int g = gid[nd];
    if (g != gcur) {
      atomicAdd(&pooled[(size_t)gcur * DHID + lane * 2], acc.x);
      atomicAdd(&pooled[(size_t)gcur * DHID + lane * 2 + 1], acc.y);
      acc = make_float2(0.f, 0.f);
      gcur = g;
    }
    const float2 v = *(const float2*)(h + (size_t)nd * DHID + lane * 2);
    acc.x += v.x;
    acc.y += v.y;
  }
  atomicAdd(&pooled[(size_t)gcur * DHID + lane * 2], acc.x);
  atomicAdd(&pooled[(size_t)gcur * DHID + lane * 2 + 1], acc.y);
}

// ---- MLP head: one block (128 thr) per graph ------------------------------
__global__ void mlp_kernel(const float* __restrict__ psu, const float* __restrict__ psv,
                           const int* __restrict__ cnt_su, const int* __restrict__ cnt_sv,
                           const float* __restrict__ gf,
                           const float* __restrict__ W0, const float* __restrict__ b0,
                           const float* __restrict__ W1, const float* __restrict__ b1,
                           const float* __restrict__ W2, const float* __restrict__ b2,
                           float* __restrict__ out) {
  int g = blockIdx.x;
  int t = threadIdx.x;  // 128 threads
  __shared__ float comb[260];
  __shared__ float h0[128];
  __shared__ float h1[64];
  float inv_su = 1.0f / (float)max(cnt_su[g], 1);
  float inv_sv = 1.0f / (float)max(cnt_sv[g], 1);
  comb[t] = psu[(size_t)g * DHID + t] * inv_su;
  comb[128 + t] = psv[(size_t)g * DHID + t] * inv_sv;
  if (t < 4) comb[256 + t] = gf[g * 4 + t];
  __syncthreads();
  float acc = b0[t];
  for (int k = 0; k < 260; ++k) acc = fmaf(comb[k], W0[k * 128 + t], acc);
  h0[t] = fmaxf(acc, 0.f);
  __syncthreads();
  if (t < 64) {
    float a = b1[t];
    for (int k = 0; k < 128; ++k) a = fmaf(h0[k], W1[k * 64 + t], a);
    h1[t] = fmaxf(a, 0.f);
  }
  __syncthreads();
  if (t < 64) {
    float p = h1[t] * W2[t];
    #pragma unroll
    for (int d = 32; d > 0; d >>= 1) p += __shfl_down(p, d);
    if (t == 0) out[g] = p + b2[0];
  }
}

// ---------------------------------------------------------------------------
extern "C" void kernel_launch(void* const* d_in, const int* in_sizes, int n_in,
                              void* d_out, int out_size, void* d_ws, size_t ws_size,
                              hipStream_t stream) {
  const float* solute_x  = (const float*)d_in[0];
  const float* solvent_x = (const float*)d_in[1];
  const float* gfeat     = (const float*)d_in[2];
  const int* su_src = (const int*)d_in[3];
  const int* su_dst = (const int*)d_in[4];
  const int* sv_src = (const int*)d_in[5];
  const int* sv_dst = (const int*)d_in[6];
  const int* su_gid = (const int*)d_in[7];
  const int* sv_gid = (const int*)d_in[8];
  const float* enc_W[2][3] = {
    {(const float*)d_in[9],  (const float*)d_in[10], (const float*)d_in[11]},
    {(const float*)d_in[13], (const float*)d_in[14], (const float*)d_in[15]}};
  const float* enc_b[2] = {(const float*)d_in[12], (const float*)d_in[16]};
  const float* mW0 = (const float*)d_in[17];
  const float* mb0 = (const float*)d_in[18];
  const float* mW1 = (const float*)d_in[19];
  const float* mb1 = (const float*)d_in[20];
  const float* mW2 = (const float*)d_in[21];
  const float* mb2 = (const float*)d_in[22];

  const int N = in_sizes[0] / 64;   // 50000
  const int E = in_sizes[3];        // 800000
  const int G = in_sizes[2] / 4;    // 256

  const int* srcs[2] = {su_src, sv_src};
  const int* dsts[2] = {su_dst, sv_dst};
  const int* gids[2] = {su_gid, sv_gid};
  const float* xs[2] = {solute_x, solvent_x};

  // workspace carve-up (256B aligned)
  char* ws = (char*)d_ws;
  size_t off = 0;
  auto alloc = [&](size_t bytes) -> void* {
    void* p = ws + off;
    off = (off + bytes + 255) & ~(size_t)255;
    return p;
  };
  const int NB = (N + 255) / 256;  // scan blocks
  int*   ibase   = (int*)alloc((size_t)3 * N * 4);      // deg_out | deg_in | fill
  int*   deg_out = ibase;
  int*   deg_in  = ibase + N;
  int*   fill    = ibase + 2 * N;
  float* nsrc    = (float*)alloc((size_t)N * 4);
  float* ndst    = (float*)alloc((size_t)N * 4);
  int*   rowptr  = (int*)alloc((size_t)(N + 1) * 4);
  int*   part    = (int*)alloc((size_t)NB * 4);
  int*   colidx  = (int*)alloc((size_t)E * 4);
  float* bufA    = (float*)alloc((size_t)N * DHID * 4);
  float* bufB    = (float*)alloc((size_t)N * DHID * 4);
  float* pbase   = (float*)alloc(((size_t)2 * G * DHID + 2 * G) * 4);
  float* pooled_su = pbase;
  float* pooled_sv = pbase + (size_t)G * DHID;
  int*   cnt_su    = (int*)(pbase + (size_t)2 * G * DHID);
  int*   cnt_sv    = cnt_su + G;
  (void)ws_size; (void)n_in; (void)out_size;

  float* pooleds[2] = {pooled_su, pooled_sv};
  int*   cnts[2]    = {cnt_su, cnt_sv};

  hipMemsetAsync(pbase, 0, ((size_t)2 * G * DHID + 2 * G) * 4, stream);

  const int TB = 256;
  const int egrid = (E + TB - 1) / TB;
  const int ngrid = (N + TB - 1) / TB;
  const int ggrid = (N + BM - 1) / BM;
  const int agrid = (N + 3) / 4;               // wave per node
  const int PC = 25;                           // nodes per wave in pool
  const int pwaves = (N + PC - 1) / PC;
  const int pgrid = (pwaves + 3) / 4;

  for (int enc = 0; enc < 2; ++enc) {
    hipMemsetAsync(ibase, 0, (size_t)3 * N * 4, stream);
    deg_kernel<<<egrid, TB, 0, stream>>>(srcs[enc], dsts[enc], deg_out, deg_in, E);
    scan_part<<<NB, 256, 0, stream>>>(deg_in, deg_out, part, nsrc, ndst, N);
    scan_mid<<<1, 256, 0, stream>>>(part, rowptr + N, NB);
    scan_final<<<NB, 256, 0, stream>>>(deg_in, part, rowptr, N);
    fill_kernel<<<egrid, TB, 0, stream>>>(srcs[enc], dsts[enc], rowptr, fill, colidx, E);

    const float* in = xs[enc];
    int K = 64;
    for (int l = 0; l < 3; ++l) {
      gemm_scaled<<<ggrid, TB, 0, stream>>>(in, enc_W[enc][l], nsrc, bufB, N, K);
      agg_kernel<<<agrid, TB, 0, stream>>>(bufB, rowptr, colidx, ndst,
                                           enc_b[enc] + l * DHID, bufA, N);
      in = bufA;
      K = DHID;
    }
    cnt_kernel<<<ngrid, TB, 0, stream>>>(gids[enc], cnts[enc], N);
    pool_kernel<<<pgrid, TB, 0, stream>>>(bufA, gids[enc], pooleds[enc], N, PC);
  }

  mlp_kernel<<<G, 128, 0, stream>>>(pooled_su, pooled_sv, cnt_su, cnt_sv, gfeat,
                                    mW0, mb0, mW1, mb1, mW2, mb2, (float*)d_out);
}

// Round 3
// 838.084 us; speedup vs baseline: 1.3988x; 1.0462x over previous
//
#include <hip/hip_runtime.h>

// ---------------------------------------------------------------------------
// DualGNN: 2x (3-layer GCN encoder + mean-pool) + MLP head. All f32.
// CSR build with ZERO global atomics:
//   hist:    LDS-privatized per-(slice,chunk) histograms of src/dst -> u16 parts
//   reduce:  sum parts -> deg, norms, per-graph cnt, scan block-sums;
//            in-place per-slice exclusive offsets for dst parts
//   scan_mid/scan_final: rowptr
//   fillrank: LDS-rank within (slice,chunk) -> colidx scatter (no atomics)
// per layer: gemm_scaled (vector-f32 tiled GEMM), agg (wave/node gather).
// ---------------------------------------------------------------------------

#define DHID 128
#define CHUNK 12800   // nodes per chunk (LDS histo: 51.2 KB)
#define SB 32         // edge slices

static __device__ __forceinline__ void fma4(float4& o, float a, const float4& w) {
  o.x = fmaf(a, w.x, o.x);
  o.y = fmaf(a, w.y, o.y);
  o.z = fmaf(a, w.z, o.z);
  o.w = fmaf(a, w.w, o.w);
}
static __device__ __forceinline__ void add4(float4& o, const float4& v) {
  o.x += v.x; o.y += v.y; o.z += v.z; o.w += v.w;
}

// ---- pass 1: privatized histograms -> u16 partials ------------------------
// grid (SB, nch, 2): z=0 counts src (deg_out), z=1 counts dst (deg_in)
__global__ __launch_bounds__(256) void hist_kernel(
    const int* __restrict__ src, const int* __restrict__ dst,
    unsigned short* __restrict__ parts, int E, int es) {
  __shared__ unsigned int h[CHUNK];
  const int t = threadIdx.x;
  const int slice = blockIdx.x;
  const int chunk = blockIdx.y;
  const int arr = blockIdx.z;
  for (int i = t; i < CHUNK; i += 256) h[i] = 0;
  __syncthreads();
  const int* __restrict__ idx = arr ? dst : src;
  const int base = chunk * CHUNK;
  const int e0 = slice * es;
  const int e1 = min(e0 + es, E);
  for (int e = e0 + t; e < e1; e += 256) {
    unsigned v = (unsigned)(idx[e] - base);
    if (v < CHUNK) atomicAdd(&h[v], 1u);
  }
  __syncthreads();
  unsigned short* p = parts + (((size_t)arr * gridDim.y + chunk) * SB + slice) * CHUNK;
  for (int i = t; i < CHUNK; i += 256) p[i] = (unsigned short)h[i];
}

// ---- pass 2: reduce partials; fused norms, cnt, scan block-sums -----------
__global__ __launch_bounds__(256) void reduce_kernel(
    unsigned short* __restrict__ parts, const int* __restrict__ gid,
    int* __restrict__ deg_in, float* __restrict__ nsrc, float* __restrict__ ndst,
    int* __restrict__ sp, int* __restrict__ cnt, int N, int nch) {
  const int t = threadIdx.x;
  const int n = blockIdx.x * 256 + t;
  int sumD = 0;
  if (n < N) {
    const int chunk = n / CHUNK;
    const int local = n % CHUNK;
    const size_t strideA = (size_t)nch * SB * CHUNK;
    const unsigned short* pS = parts + ((size_t)chunk * SB) * CHUNK + local;
    unsigned short* pD = parts + strideA + ((size_t)chunk * SB) * CHUNK + local;
    int sumS = 0;
    #pragma unroll 8
    for (int s = 0; s < SB; ++s) sumS += pS[(size_t)s * CHUNK];
    for (int s = 0; s < SB; ++s) {
      int v = pD[(size_t)s * CHUNK];
      pD[(size_t)s * CHUNK] = (unsigned short)sumD;  // per-slice exclusive offset
      sumD += v;
    }
    deg_in[n] = sumD;
    nsrc[n] = 1.0f / sqrtf((float)max(sumS, 1));
    ndst[n] = 1.0f / sqrtf((float)max(sumD, 1));
    atomicAdd(&cnt[gid[n]], 1);
  }
  // block total of deg_in -> sp[blockIdx.x]
  int v = sumD;
  #pragma unroll
  for (int d = 32; d > 0; d >>= 1) v += __shfl_xor(v, d);
  __shared__ int ws[4];
  if ((t & 63) == 0) ws[t >> 6] = v;
  __syncthreads();
  if (t == 0) sp[blockIdx.x] = ws[0] + ws[1] + ws[2] + ws[3];
}

// ---- scan of block sums (single block, nb<=256) ---------------------------
__global__ void scan_mid(int* __restrict__ part, int* __restrict__ total_out, int nb) {
  const int tid = threadIdx.x;
  const int lane = tid & 63;
  const int wv = tid >> 6;
  int v = (tid < nb) ? part[tid] : 0;
  int x = v;
  #pragma unroll
  for (int d = 1; d < 64; d <<= 1) {
    int y = __shfl_up(x, d);
    if (lane >= d) x += y;
  }
  __shared__ int ws[4];
  if (lane == 63) ws[wv] = x;
  __syncthreads();
  int woff = 0;
  for (int k = 0; k < wv; ++k) woff += ws[k];
  if (tid < nb) part[tid] = woff + x - v;
  if (tid == 255) *total_out = woff + x;
}

// ---- block-local exclusive scan + block offset -> rowptr ------------------
__global__ void scan_final(const int* __restrict__ deg, const int* __restrict__ part,
                           int* __restrict__ rowptr, int n) {
  const int tid = threadIdx.x;
  const int i = blockIdx.x * 256 + tid;
  const int lane = tid & 63;
  const int wv = tid >> 6;
  int v = (i < n) ? deg[i] : 0;
  int x = v;
  #pragma unroll
  for (int d = 1; d < 64; d <<= 1) {
    int y = __shfl_up(x, d);
    if (lane >= d) x += y;
  }
  __shared__ int ws[4];
  if (lane == 63) ws[wv] = x;
  __syncthreads();
  int woff = 0;
  for (int k = 0; k < wv; ++k) woff += ws[k];
  if (i < n) rowptr[i] = part[blockIdx.x] + woff + x - v;
}

// ---- pass 3: LDS rank + scatter -> colidx (no global atomics) -------------
__global__ __launch_bounds__(256) void fillrank_kernel(
    const int* __restrict__ src, const int* __restrict__ dst,
    const unsigned short* __restrict__ partD, const int* __restrict__ rowptr,
    int* __restrict__ colidx, int E, int es) {
  __shared__ unsigned int h[CHUNK];
  const int t = threadIdx.x;
  const int slice = blockIdx.x;
  const int chunk = blockIdx.y;
  for (int i = t; i < CHUNK; i += 256) h[i] = 0;
  __syncthreads();
  const int base = chunk * CHUNK;
  const unsigned short* __restrict__ po = partD + ((size_t)chunk * SB + slice) * CHUNK;
  const int e0 = slice * es;
  const int e1 = min(e0 + es, E);
  for (int e = e0 + t; e < e1; e += 256) {
    int d = dst[e];
    unsigned v = (unsigned)(d - base);
    if (v < CHUNK) {
      int rank = (int)atomicAdd(&h[v], 1u);
      int slot = rowptr[d] + (int)po[v] + rank;
      colidx[slot] = src[e];
    }
  }
}

// ---- tiled GEMM: out[n][c] = nsrc[n] * sum_k A[n][k]*W[k][c], C=128 -------
#define BM 128
#define BKC 32
__global__ __launch_bounds__(256) void gemm_scaled(
    const float* __restrict__ A, const float* __restrict__ W,
    const float* __restrict__ nsrc, float* __restrict__ out,
    int nrows, int K) {
  __shared__ __align__(16) float As[BM][BKC + 4];
  __shared__ __align__(16) float Ws[BKC][DHID];
  const int tid = threadIdx.x;
  const int row0 = blockIdx.x * BM;
  const int cx = tid & 15;
  const int ry = tid >> 4;
  const int lr = tid >> 1;
  const int lk = (tid & 1) * 16;
  const int wk = tid >> 3;
  const int wc = (tid & 7) * 4;

  float4 acc[8][2];
  #pragma unroll
  for (int r = 0; r < 8; ++r) {
    acc[r][0] = make_float4(0.f, 0.f, 0.f, 0.f);
    acc[r][1] = make_float4(0.f, 0.f, 0.f, 0.f);
  }

  const int arow = row0 + lr;
  const float scale = (arow < nrows) ? nsrc[arow] : 0.f;

  for (int k0 = 0; k0 < K; k0 += BKC) {
    if (arow < nrows) {
      const float4* ap = (const float4*)(A + (size_t)arow * K + k0 + lk);
      #pragma unroll
      for (int j = 0; j < 4; ++j) {
        float4 v = ap[j];
        v.x *= scale; v.y *= scale; v.z *= scale; v.w *= scale;
        *(float4*)&As[lr][lk + j * 4] = v;
      }
    } else {
      #pragma unroll
      for (int j = 0; j < 4; ++j)
        *(float4*)&As[lr][lk + j * 4] = make_float4(0.f, 0.f, 0.f, 0.f);
    }
    {
      const float* wp = W + (size_t)(k0 + wk) * DHID;
      #pragma unroll
      for (int j = 0; j < 4; ++j)
        *(float4*)&Ws[wk][wc + j * 32] = *(const float4*)(wp + wc + j * 32);
    }
    __syncthreads();
    #pragma unroll 4
    for (int kk = 0; kk < BKC; kk += 2) {
      float4 w00 = *(float4*)&Ws[kk][cx * 4];
      float4 w01 = *(float4*)&Ws[kk][64 + cx * 4];
      float4 w10 = *(float4*)&Ws[kk + 1][cx * 4];
      float4 w11 = *(float4*)&Ws[kk + 1][64 + cx * 4];
      #pragma unroll
      for (int r = 0; r < 8; ++r) {
        float2 a = *(float2*)&As[ry + 16 * r][kk];
        fma4(acc[r][0], a.x, w00);
        fma4(acc[r][1], a.x, w01);
        fma4(acc[r][0], a.y, w10);
        fma4(acc[r][1], a.y, w11);
      }
    }
    __syncthreads();
  }
  #pragma unroll
  for (int r = 0; r < 8; ++r) {
    int row = row0 + ry + 16 * r;
    if (row < nrows) {
      float* op = out + (size_t)row * DHID;
      *(float4*)(op + cx * 4) = acc[r][0];
      *(float4*)(op + 64 + cx * 4) = acc[r][1];
    }
  }
}

// ---- aggregation: wave/node, shfl-broadcast colidx, float4 half-wave ------
__global__ void agg_kernel(const float* __restrict__ hB, const int* __restrict__ rowptr,
                           const int* __restrict__ colidx, const float* __restrict__ ndst,
                           const float* __restrict__ bias, float* __restrict__ out, int N) {
  int wid = (blockIdx.x * blockDim.x + threadIdx.x) >> 6;
  int lane = threadIdx.x & 63;
  if (wid >= N) return;
  int beg = rowptr[wid];
  int end = rowptr[wid + 1];
  const int half = lane >> 5;
  const int col = (lane & 31) * 4;
  float4 acc = make_float4(0.f, 0.f, 0.f, 0.f);

  for (int c0 = beg; c0 < end; c0 += 64) {
    int cnt = min(end - c0, 64);
    int myidx = (lane < cnt) ? colidx[c0 + lane] : 0;
    int pairs = cnt >> 1;
    int j = 0;
    for (; j + 4 <= pairs; j += 4) {
      int s0 = __shfl(myidx, 2 * j + half);
      int s1 = __shfl(myidx, 2 * j + 2 + half);
      int s2 = __shfl(myidx, 2 * j + 4 + half);
      int s3 = __shfl(myidx, 2 * j + 6 + half);
      float4 v0 = *(const float4*)(hB + (size_t)s0 * DHID + col);
      float4 v1 = *(const float4*)(hB + (size_t)s1 * DHID + col);
      float4 v2 = *(const float4*)(hB + (size_t)s2 * DHID + col);
      float4 v3 = *(const float4*)(hB + (size_t)s3 * DHID + col);
      add4(acc, v0); add4(acc, v1); add4(acc, v2); add4(acc, v3);
    }
    for (; j < pairs; ++j) {
      int s = __shfl(myidx, 2 * j + half);
      float4 v = *(const float4*)(hB + (size_t)s * DHID + col);
      add4(acc, v);
    }
    if (cnt & 1) {
      int s = __shfl(myidx, cnt - 1);
      if (half == 0) {
        float4 v = *(const float4*)(hB + (size_t)s * DHID + col);
        add4(acc, v);
      }
    }
  }
  acc.x += __shfl_xor(acc.x, 32);
  acc.y += __shfl_xor(acc.y, 32);
  acc.z += __shfl_xor(acc.z, 32);
  acc.w += __shfl_xor(acc.w, 32);
  if (half == 0) {
    float nd = ndst[wid];
    float4 b = *(const float4*)(bias + col);
    float4 o;
    o.x = fmaxf(fmaf(acc.x, nd, b.x), 0.f);
    o.y = fmaxf(fmaf(acc.y, nd, b.y), 0.f);
    o.z = fmaxf(fmaf(acc.z, nd, b.z), 0.f);
    o.w = fmaxf(fmaf(acc.w, nd, b.w), 0.f);
    *(float4*)(out + (size_t)wid * DHID + col) = o;
  }
}

// ---- mean-pool numerator: run-flush over sorted gid -----------------------
__global__ void pool_kernel(const float* __restrict__ h, const int* __restrict__ gid,
                            float* __restrict__ pooled, int N, int C) {
  int wid = (blockIdx.x * blockDim.x + threadIdx.x) >> 6;
  int lane = threadIdx.x & 63;
  int n0 = wid * C;
  if (n0 >= N) return;
  int n1 = min(n0 + C, N);
  int gcur = gid[n0];
  float2 acc = make_float2(0.f, 0.f);
  for (int nd = n0; nd < n1; ++nd) {
    int g = gid[nd];
    if (g != gcur) {
      atomicAdd(&pooled[(size_t)gcur * DHID + lane * 2], acc.x);
      atomicAdd(&pooled[(size_t)gcur * DHID + lane * 2 + 1], acc.y);
      acc = make_float2(0.f, 0.f);
      gcur = g;
    }
    const float2 v = *(const float2*)(h + (size_t)nd * DHID + lane * 2);
    acc.x += v.x;
    acc.y += v.y;
  }
  atomicAdd(&pooled[(size_t)gcur * DHID + lane * 2], acc.x);
  atomicAdd(&pooled[(size_t)gcur * DHID + lane * 2 + 1], acc.y);
}

// ---- MLP head: one block (128 thr) per graph ------------------------------
__global__ void mlp_kernel(const float* __restrict__ psu, const float* __restrict__ psv,
                           const int* __restrict__ cnt_su, const int* __restrict__ cnt_sv,
                           const float* __restrict__ gf,
                           const float* __restrict__ W0, const float* __restrict__ b0,
                           const float* __restrict__ W1, const float* __restrict__ b1,
                           const float* __restrict__ W2, const float* __restrict__ b2,
                           float* __restrict__ out) {
  int g = blockIdx.x;
  int t = threadIdx.x;  // 128 threads
  __shared__ float comb[260];
  __shared__ float h0[128];
  __shared__ float h1[64];
  float inv_su = 1.0f / (float)max(cnt_su[g], 1);
  float inv_sv = 1.0f / (float)max(cnt_sv[g], 1);
  comb[t] = psu[(size_t)g * DHID + t] * inv_su;
  comb[128 + t] = psv[(size_t)g * DHID + t] * inv_sv;
  if (t < 4) comb[256 + t] = gf[g * 4 + t];
  __syncthreads();
  float acc = b0[t];
  for (int k = 0; k < 260; ++k) acc = fmaf(comb[k], W0[k * 128 + t], acc);
  h0[t] = fmaxf(acc, 0.f);
  __syncthreads();
  if (t < 64) {
    float a = b1[t];
    for (int k = 0; k < 128; ++k) a = fmaf(h0[k], W1[k * 64 + t], a);
    h1[t] = fmaxf(a, 0.f);
  }
  __syncthreads();
  if (t < 64) {
    float p = h1[t] * W2[t];
    #pragma unroll
    for (int d = 32; d > 0; d >>= 1) p += __shfl_down(p, d);
    if (t == 0) out[g] = p + b2[0];
  }
}

// ---------------------------------------------------------------------------
extern "C" void kernel_launch(void* const* d_in, const int* in_sizes, int n_in,
                              void* d_out, int out_size, void* d_ws, size_t ws_size,
                              hipStream_t stream) {
  const float* solute_x  = (const float*)d_in[0];
  const float* solvent_x = (const float*)d_in[1];
  const float* gfeat     = (const float*)d_in[2];
  const int* su_src = (const int*)d_in[3];
  const int* su_dst = (const int*)d_in[4];
  const int* sv_src = (const int*)d_in[5];
  const int* sv_dst = (const int*)d_in[6];
  const int* su_gid = (const int*)d_in[7];
  const int* sv_gid = (const int*)d_in[8];
  const float* enc_W[2][3] = {
    {(const float*)d_in[9],  (const float*)d_in[10], (const float*)d_in[11]},
    {(const float*)d_in[13], (const float*)d_in[14], (const float*)d_in[15]}};
  const float* enc_b[2] = {(const float*)d_in[12], (const float*)d_in[16]};
  const float* mW0 = (const float*)d_in[17];
  const float* mb0 = (const float*)d_in[18];
  const float* mW1 = (const float*)d_in[19];
  const float* mb1 = (const float*)d_in[20];
  const float* mW2 = (const float*)d_in[21];
  const float* mb2 = (const float*)d_in[22];

  const int N = in_sizes[0] / 64;   // 50000
  const int E = in_sizes[3];        // 800000
  const int G = in_sizes[2] / 4;    // 256

  const int* srcs[2] = {su_src, sv_src};
  const int* dsts[2] = {su_dst, sv_dst};
  const int* gids[2] = {su_gid, sv_gid};
  const float* xs[2] = {solute_x, solvent_x};

  // workspace carve-up (256B aligned)
  char* ws = (char*)d_ws;
  size_t off = 0;
  auto alloc = [&](size_t bytes) -> void* {
    void* p = ws + off;
    off = (off + bytes + 255) & ~(size_t)255;
    return p;
  };
  const int NB = (N + 255) / 256;            // rowptr scan blocks (196)
  const int NCH = (N + CHUNK - 1) / CHUNK;   // chunks (4)
  const int RB = (NCH * CHUNK + 255) / 256;  // reduce blocks (200)
  const int ES = (E + SB - 1) / SB;          // edges per slice (25000)
  const size_t arrStride = (size_t)NCH * SB * CHUNK;  // u16 elems per array

  int*   deg_in  = (int*)alloc((size_t)N * 4);
  float* nsrc    = (float*)alloc((size_t)N * 4);
  float* ndst    = (float*)alloc((size_t)N * 4);
  int*   rowptr  = (int*)alloc((size_t)(N + 1) * 4);
  int*   sp      = (int*)alloc((size_t)RB * 4);
  unsigned short* parts = (unsigned short*)alloc(2 * arrStride * 2);
  int*   colidx  = (int*)alloc((size_t)E * 4);
  float* bufA    = (float*)alloc((size_t)N * DHID * 4);
  float* bufB    = (float*)alloc((size_t)N * DHID * 4);
  float* pbase   = (float*)alloc(((size_t)2 * G * DHID + 2 * G) * 4);
  float* pooled_su = pbase;
  float* pooled_sv = pbase + (size_t)G * DHID;
  int*   cnt_su    = (int*)(pbase + (size_t)2 * G * DHID);
  int*   cnt_sv    = cnt_su + G;
  (void)ws_size; (void)n_in; (void)out_size;

  float* pooleds[2] = {pooled_su, pooled_sv};
  int*   cnts[2]    = {cnt_su, cnt_sv};

  hipMemsetAsync(pbase, 0, ((size_t)2 * G * DHID + 2 * G) * 4, stream);

  const int TB = 256;
  const int ggrid = (N + BM - 1) / BM;
  const int agrid = (N + 3) / 4;               // wave per node
  const int PC = 25;                           // nodes per wave in pool
  const int pwaves = (N + PC - 1) / PC;
  const int pgrid = (pwaves + 3) / 4;

  for (int enc = 0; enc < 2; ++enc) {
    hist_kernel<<<dim3(SB, NCH, 2), TB, 0, stream>>>(srcs[enc], dsts[enc], parts, E, ES);
    reduce_kernel<<<RB, TB, 0, stream>>>(parts, gids[enc], deg_in, nsrc, ndst,
                                         sp, cnts[enc], N, NCH);
    scan_mid<<<1, 256, 0, stream>>>(sp, rowptr + N, NB);
    scan_final<<<NB, 256, 0, stream>>>(deg_in, sp, rowptr, N);
    fillrank_kernel<<<dim3(SB, NCH), TB, 0, stream>>>(srcs[enc], dsts[enc],
                                                      parts + arrStride, rowptr,
                                                      colidx, E, ES);

    const float* in = xs[enc];
    int K = 64;
    for (int l = 0; l < 3; ++l) {
      gemm_scaled<<<ggrid, TB, 0, stream>>>(in, enc_W[enc][l], nsrc, bufB, N, K);
      agg_kernel<<<agrid, TB, 0, stream>>>(bufB, rowptr, colidx, ndst,
                                           enc_b[enc] + l * DHID, bufA, N);
      in = bufA;
      K = DHID;
    }
    pool_kernel<<<pgrid, TB, 0, stream>>>(bufA, gids[enc], pooleds[enc], N, PC);
  }

  mlp_kernel<<<G, 128, 0, stream>>>(pooled_su, pooled_sv, cnt_su, cnt_sv, gfeat,
                                    mW0, mb0, mW1, mb1, mW2, mb2, (float*)d_out);
}

// Round 4
// 718.468 us; speedup vs baseline: 1.6317x; 1.1665x over previous
//
#include <hip/hip_runtime.h>

// ---------------------------------------------------------------------------
// DualGNN: 2x (3-layer GCN encoder + mean-pool) + MLP head. All f32.
// CSR build with ZERO global atomics:
//   hist:    LDS-privatized per-(slice,chunk) histograms of src/dst -> u16 parts
//   reduce:  register-batched partial sums -> deg, norms, scan block-sums;
//            in-place per-slice exclusive offsets for dst parts (all loads
//            issued independently before the register prefix scan)
//   scan_mid/scan_final: rowptr
//   fillrank: LDS-rank within (slice,chunk) -> colidx scatter (no atomics)
// per layer: gemm_scaled (vector-f32 tiled GEMM), agg (wave/node gather).
// pool: run-flush over sorted gid, fused per-graph node counting.
// ---------------------------------------------------------------------------

#define DHID 128
#define CHUNK 12800   // nodes per chunk (LDS histo: 51.2 KB)
#define SB 32         // edge slices

static __device__ __forceinline__ void fma4(float4& o, float a, const float4& w) {
  o.x = fmaf(a, w.x, o.x);
  o.y = fmaf(a, w.y, o.y);
  o.z = fmaf(a, w.z, o.z);
  o.w = fmaf(a, w.w, o.w);
}
static __device__ __forceinline__ void add4(float4& o, const float4& v) {
  o.x += v.x; o.y += v.y; o.z += v.z; o.w += v.w;
}

// ---- pass 1: privatized histograms -> u16 partials ------------------------
// grid (SB, nch, 2): z=0 counts src (deg_out), z=1 counts dst (deg_in)
__global__ __launch_bounds__(256) void hist_kernel(
    const int* __restrict__ src, const int* __restrict__ dst,
    unsigned short* __restrict__ parts, int E, int es) {
  __shared__ unsigned int h[CHUNK];
  const int t = threadIdx.x;
  const int slice = blockIdx.x;
  const int chunk = blockIdx.y;
  const int arr = blockIdx.z;
  for (int i = t; i < CHUNK; i += 256) h[i] = 0;
  __syncthreads();
  const int* __restrict__ idx = arr ? dst : src;
  const int base = chunk * CHUNK;
  const int e0 = slice * es;
  const int e1 = min(e0 + es, E);
  for (int e = e0 + t; e < e1; e += 256) {
    unsigned v = (unsigned)(idx[e] - base);
    if (v < CHUNK) atomicAdd(&h[v], 1u);
  }
  __syncthreads();
  unsigned short* p = parts + (((size_t)arr * gridDim.y + chunk) * SB + slice) * CHUNK;
  for (int i = t; i < CHUNK; i += 256) p[i] = (unsigned short)h[i];
}

// ---- pass 2: register-batched reduce of partials --------------------------
// All SB loads issued independently (register arrays, full unroll); prefix
// scan for dst offsets in registers; batched stores. No atomics.
__global__ __launch_bounds__(256) void reduce_kernel(
    unsigned short* __restrict__ parts,
    int* __restrict__ deg_in, float* __restrict__ nsrc, float* __restrict__ ndst,
    int* __restrict__ sp, int N, int nch) {
  const int t = threadIdx.x;
  const int n = blockIdx.x * 256 + t;
  int sumD = 0;
  if (n < N) {
    const int chunk = n / CHUNK;
    const int local = n % CHUNK;
    const size_t strideA = (size_t)nch * SB * CHUNK;
    const unsigned short* __restrict__ pS = parts + ((size_t)chunk * SB) * CHUNK + local;
    unsigned short* __restrict__ pD = parts + strideA + ((size_t)chunk * SB) * CHUNK + local;
    unsigned short vS[SB], vD[SB];
    #pragma unroll
    for (int s = 0; s < SB; ++s) vS[s] = pS[(size_t)s * CHUNK];
    #pragma unroll
    for (int s = 0; s < SB; ++s) vD[s] = pD[(size_t)s * CHUNK];
    int sumS = 0;
    #pragma unroll
    for (int s = 0; s < SB; ++s) sumS += (int)vS[s];
    #pragma unroll
    for (int s = 0; s < SB; ++s) {
      int c = (int)vD[s];
      vD[s] = (unsigned short)sumD;   // per-slice exclusive offset
      sumD += c;
    }
    #pragma unroll
    for (int s = 0; s < SB; ++s) pD[(size_t)s * CHUNK] = vD[s];
    deg_in[n] = sumD;
    nsrc[n] = 1.0f / sqrtf((float)max(sumS, 1));
    ndst[n] = 1.0f / sqrtf((float)max(sumD, 1));
  }
  // block total of deg_in -> sp[blockIdx.x]
  int v = sumD;
  #pragma unroll
  for (int d = 32; d > 0; d >>= 1) v += __shfl_xor(v, d);
  __shared__ int ws[4];
  if ((t & 63) == 0) ws[t >> 6] = v;
  __syncthreads();
  if (t == 0) sp[blockIdx.x] = ws[0] + ws[1] + ws[2] + ws[3];
}

// ---- scan of block sums (single block, nb<=256) ---------------------------
__global__ void scan_mid(int* __restrict__ part, int* __restrict__ total_out, int nb) {
  const int tid = threadIdx.x;
  const int lane = tid & 63;
  const int wv = tid >> 6;
  int v = (tid < nb) ? part[tid] : 0;
  int x = v;
  #pragma unroll
  for (int d = 1; d < 64; d <<= 1) {
    int y = __shfl_up(x, d);
    if (lane >= d) x += y;
  }
  __shared__ int ws[4];
  if (lane == 63) ws[wv] = x;
  __syncthreads();
  int woff = 0;
  for (int k = 0; k < wv; ++k) woff += ws[k];
  if (tid < nb) part[tid] = woff + x - v;
  if (tid == 255) *total_out = woff + x;
}

// ---- block-local exclusive scan + block offset -> rowptr ------------------
__global__ void scan_final(const int* __restrict__ deg, const int* __restrict__ part,
                           int* __restrict__ rowptr, int n) {
  const int tid = threadIdx.x;
  const int i = blockIdx.x * 256 + tid;
  const int lane = tid & 63;
  const int wv = tid >> 6;
  int v = (i < n) ? deg[i] : 0;
  int x = v;
  #pragma unroll
  for (int d = 1; d < 64; d <<= 1) {
    int y = __shfl_up(x, d);
    if (lane >= d) x += y;
  }
  __shared__ int ws[4];
  if (lane == 63) ws[wv] = x;
  __syncthreads();
  int woff = 0;
  for (int k = 0; k < wv; ++k) woff += ws[k];
  if (i < n) rowptr[i] = part[blockIdx.x] + woff + x - v;
}

// ---- pass 3: LDS rank + scatter -> colidx (no global atomics) -------------
__global__ __launch_bounds__(256) void fillrank_kernel(
    const int* __restrict__ src, const int* __restrict__ dst,
    const unsigned short* __restrict__ partD, const int* __restrict__ rowptr,
    int* __restrict__ colidx, int E, int es) {
  __shared__ unsigned int h[CHUNK];
  const int t = threadIdx.x;
  const int slice = blockIdx.x;
  const int chunk = blockIdx.y;
  for (int i = t; i < CHUNK; i += 256) h[i] = 0;
  __syncthreads();
  const int base = chunk * CHUNK;
  const unsigned short* __restrict__ po = partD + ((size_t)chunk * SB + slice) * CHUNK;
  const int e0 = slice * es;
  const int e1 = min(e0 + es, E);
  for (int e = e0 + t; e < e1; e += 256) {
    int d = dst[e];
    unsigned v = (unsigned)(d - base);
    if (v < CHUNK) {
      int rank = (int)atomicAdd(&h[v], 1u);
      int slot = rowptr[d] + (int)po[v] + rank;
      colidx[slot] = src[e];
    }
  }
}

// ---- tiled GEMM: out[n][c] = nsrc[n] * sum_k A[n][k]*W[k][c], C=128 -------
#define BM 128
#define BKC 32
__global__ __launch_bounds__(256) void gemm_scaled(
    const float* __restrict__ A, const float* __restrict__ W,
    const float* __restrict__ nsrc, float* __restrict__ out,
    int nrows, int K) {
  __shared__ __align__(16) float As[BM][BKC + 4];
  __shared__ __align__(16) float Ws[BKC][DHID];
  const int tid = threadIdx.x;
  const int row0 = blockIdx.x * BM;
  const int cx = tid & 15;
  const int ry = tid >> 4;
  const int lr = tid >> 1;
  const int lk = (tid & 1) * 16;
  const int wk = tid >> 3;
  const int wc = (tid & 7) * 4;

  float4 acc[8][2];
  #pragma unroll
  for (int r = 0; r < 8; ++r) {
    acc[r][0] = make_float4(0.f, 0.f, 0.f, 0.f);
    acc[r][1] = make_float4(0.f, 0.f, 0.f, 0.f);
  }

  const int arow = row0 + lr;
  const float scale = (arow < nrows) ? nsrc[arow] : 0.f;

  for (int k0 = 0; k0 < K; k0 += BKC) {
    if (arow < nrows) {
      const float4* ap = (const float4*)(A + (size_t)arow * K + k0 + lk);
      #pragma unroll
      for (int j = 0; j < 4; ++j) {
        float4 v = ap[j];
        v.x *= scale; v.y *= scale; v.z *= scale; v.w *= scale;
        *(float4*)&As[lr][lk + j * 4] = v;
      }
    } else {
      #pragma unroll
      for (int j = 0; j < 4; ++j)
        *(float4*)&As[lr][lk + j * 4] = make_float4(0.f, 0.f, 0.f, 0.f);
    }
    {
      const float* wp = W + (size_t)(k0 + wk) * DHID;
      #pragma unroll
      for (int j = 0; j < 4; ++j)
        *(float4*)&Ws[wk][wc + j * 32] = *(const float4*)(wp + wc + j * 32);
    }
    __syncthreads();
    #pragma unroll 4
    for (int kk = 0; kk < BKC; kk += 2) {
      float4 w00 = *(float4*)&Ws[kk][cx * 4];
      float4 w01 = *(float4*)&Ws[kk][64 + cx * 4];
      float4 w10 = *(float4*)&Ws[kk + 1][cx * 4];
      float4 w11 = *(float4*)&Ws[kk + 1][64 + cx * 4];
      #pragma unroll
      for (int r = 0; r < 8; ++r) {
        float2 a = *(float2*)&As[ry + 16 * r][kk];
        fma4(acc[r][0], a.x, w00);
        fma4(acc[r][1], a.x, w01);
        fma4(acc[r][0], a.y, w10);
        fma4(acc[r][1], a.y, w11);
      }
    }
    __syncthreads();
  }
  #pragma unroll
  for (int r = 0; r < 8; ++r) {
    int row = row0 + ry + 16 * r;
    if (row < nrows) {
      float* op = out + (size_t)row * DHID;
      *(float4*)(op + cx * 4) = acc[r][0];
      *(float4*)(op + 64 + cx * 4) = acc[r][1];
    }
  }
}

// ---- aggregation: wave/node, shfl-broadcast colidx, float4 half-wave ------
__global__ void agg_kernel(const float* __restrict__ hB, const int* __restrict__ rowptr,
                           const int* __restrict__ colidx, const float* __restrict__ ndst,
                           const float* __restrict__ bias, float* __restrict__ out, int N) {
  int wid = (blockIdx.x * blockDim.x + threadIdx.x) >> 6;
  int lane = threadIdx.x & 63;
  if (wid >= N) return;
  int beg = rowptr[wid];
  int end = rowptr[wid + 1];
  const int half = lane >> 5;
  const int col = (lane & 31) * 4;
  float4 acc = make_float4(0.f, 0.f, 0.f, 0.f);

  for (int c0 = beg; c0 < end; c0 += 64) {
    int cnt = min(end - c0, 64);
    int myidx = (lane < cnt) ? colidx[c0 + lane] : 0;
    int pairs = cnt >> 1;
    int j = 0;
    for (; j + 4 <= pairs; j += 4) {
      int s0 = __shfl(myidx, 2 * j + half);
      int s1 = __shfl(myidx, 2 * j + 2 + half);
      int s2 = __shfl(myidx, 2 * j + 4 + half);
      int s3 = __shfl(myidx, 2 * j + 6 + half);
      float4 v0 = *(const float4*)(hB + (size_t)s0 * DHID + col);
      float4 v1 = *(const float4*)(hB + (size_t)s1 * DHID + col);
      float4 v2 = *(const float4*)(hB + (size_t)s2 * DHID + col);
      float4 v3 = *(const float4*)(hB + (size_t)s3 * DHID + col);
      add4(acc, v0); add4(acc, v1); add4(acc, v2); add4(acc, v3);
    }
    for (; j < pairs; ++j) {
      int s = __shfl(myidx, 2 * j + half);
      float4 v = *(const float4*)(hB + (size_t)s * DHID + col);
      add4(acc, v);
    }
    if (cnt & 1) {
      int s = __shfl(myidx, cnt - 1);
      if (half == 0) {
        float4 v = *(const float4*)(hB + (size_t)s * DHID + col);
        add4(acc, v);
      }
    }
  }
  acc.x += __shfl_xor(acc.x, 32);
  acc.y += __shfl_xor(acc.y, 32);
  acc.z += __shfl_xor(acc.z, 32);
  acc.w += __shfl_xor(acc.w, 32);
  if (half == 0) {
    float nd = ndst[wid];
    float4 b = *(const float4*)(bias + col);
    float4 o;
    o.x = fmaxf(fmaf(acc.x, nd, b.x), 0.f);
    o.y = fmaxf(fmaf(acc.y, nd, b.y), 0.f);
    o.z = fmaxf(fmaf(acc.z, nd, b.z), 0.f);
    o.w = fmaxf(fmaf(acc.w, nd, b.w), 0.f);
    *(float4*)(out + (size_t)wid * DHID + col) = o;
  }
}

// ---- mean-pool: run-flush over sorted gid, fused per-graph counting -------
__global__ void pool_kernel(const float* __restrict__ h, const int* __restrict__ gid,
                            float* __restrict__ pooled, int* __restrict__ cnt,
                            int N, int C) {
  int wid = (blockIdx.x * blockDim.x + threadIdx.x) >> 6;
  int lane = threadIdx.x & 63;
  int n0 = wid * C;
  if (n0 >= N) return;
  int n1 = min(n0 + C, N);
  int gcur = gid[n0];
  int runcnt = 0;
  float2 acc = make_float2(0.f, 0.f);
  for (int nd = n0; nd < n1; ++nd) {
    int g = gid[nd];
    if (g != gcur) {
      atomicAdd(&pooled[(size_t)gcur * DHID + lane * 2], acc.x);
      atomicAdd(&pooled[(size_t)gcur * DHID + lane * 2 + 1], acc.y);
      if (lane == 0) atomicAdd(&cnt[gcur], runcnt);
      acc = make_float2(0.f, 0.f);
      runcnt = 0;
      gcur = g;
    }
    const float2 v = *(const float2*)(h + (size_t)nd * DHID + lane * 2);
    acc.x += v.x;
    acc.y += v.y;
    ++runcnt;
  }
  atomicAdd(&pooled[(size_t)gcur * DHID + lane * 2], acc.x);
  atomicAdd(&pooled[(size_t)gcur * DHID + lane * 2 + 1], acc.y);
  if (lane == 0) atomicAdd(&cnt[gcur], runcnt);
}

// ---- MLP head: one block (128 thr) per graph ------------------------------
__global__ void mlp_kernel(const float* __restrict__ psu, const float* __restrict__ psv,
                           const int* __restrict__ cnt_su, const int* __restrict__ cnt_sv,
                           const float* __restrict__ gf,
                           const float* __restrict__ W0, const float* __restrict__ b0,
                           const float* __restrict__ W1, const float* __restrict__ b1,
                           const float* __restrict__ W2, const float* __restrict__ b2,
                           float* __restrict__ out) {
  int g = blockIdx.x;
  int t = threadIdx.x;  // 128 threads
  __shared__ float comb[260];
  __shared__ float h0[128];
  __shared__ float h1[64];
  float inv_su = 1.0f / (float)max(cnt_su[g], 1);
  float inv_sv = 1.0f / (float)max(cnt_sv[g], 1);
  comb[t] = psu[(size_t)g * DHID + t] * inv_su;
  comb[128 + t] = psv[(size_t)g * DHID + t] * inv_sv;
  if (t < 4) comb[256 + t] = gf[g * 4 + t];
  __syncthreads();
  float acc = b0[t];
  for (int k = 0; k < 260; ++k) acc = fmaf(comb[k], W0[k * 128 + t], acc);
  h0[t] = fmaxf(acc, 0.f);
  __syncthreads();
  if (t < 64) {
    float a = b1[t];
    for (int k = 0; k < 128; ++k) a = fmaf(h0[k], W1[k * 64 + t], a);
    h1[t] = fmaxf(a, 0.f);
  }
  __syncthreads();
  if (t < 64) {
    float p = h1[t] * W2[t];
    #pragma unroll
    for (int d = 32; d > 0; d >>= 1) p += __shfl_down(p, d);
    if (t == 0) out[g] = p + b2[0];
  }
}

// ---------------------------------------------------------------------------
extern "C" void kernel_launch(void* const* d_in, const int* in_sizes, int n_in,
                              void* d_out, int out_size, void* d_ws, size_t ws_size,
                              hipStream_t stream) {
  const float* solute_x  = (const float*)d_in[0];
  const float* solvent_x = (const float*)d_in[1];
  const float* gfeat     = (const float*)d_in[2];
  const int* su_src = (const int*)d_in[3];
  const int* su_dst = (const int*)d_in[4];
  const int* sv_src = (const int*)d_in[5];
  const int* sv_dst = (const int*)d_in[6];
  const int* su_gid = (const int*)d_in[7];
  const int* sv_gid = (const int*)d_in[8];
  const float* enc_W[2][3] = {
    {(const float*)d_in[9],  (const float*)d_in[10], (const float*)d_in[11]},
    {(const float*)d_in[13], (const float*)d_in[14], (const float*)d_in[15]}};
  const float* enc_b[2] = {(const float*)d_in[12], (const float*)d_in[16]};
  const float* mW0 = (const float*)d_in[17];
  const float* mb0 = (const float*)d_in[18];
  const float* mW1 = (const float*)d_in[19];
  const float* mb1 = (const float*)d_in[20];
  const float* mW2 = (const float*)d_in[21];
  const float* mb2 = (const float*)d_in[22];

  const int N = in_sizes[0] / 64;   // 50000
  const int E = in_sizes[3];        // 800000
  const int G = in_sizes[2] / 4;    // 256

  const int* srcs[2] = {su_src, sv_src};
  const int* dsts[2] = {su_dst, sv_dst};
  const int* gids[2] = {su_gid, sv_gid};
  const float* xs[2] = {solute_x, solvent_x};

  // workspace carve-up (256B aligned)
  char* ws = (char*)d_ws;
  size_t off = 0;
  auto alloc = [&](size_t bytes) -> void* {
    void* p = ws + off;
    off = (off + bytes + 255) & ~(size_t)255;
    return p;
  };
  const int NB = (N + 255) / 256;            // rowptr scan blocks (196)
  const int NCH = (N + CHUNK - 1) / CHUNK;   // chunks (4)
  const int RB = (NCH * CHUNK + 255) / 256;  // reduce blocks (200)
  const int ES = (E + SB - 1) / SB;          // edges per slice (25000)
  const size_t arrStride = (size_t)NCH * SB * CHUNK;  // u16 elems per array

  int*   deg_in  = (int*)alloc((size_t)N * 4);
  float* nsrc    = (float*)alloc((size_t)N * 4);
  float* ndst    = (float*)alloc((size_t)N * 4);
  int*   rowptr  = (int*)alloc((size_t)(N + 1) * 4);
  int*   sp      = (int*)alloc((size_t)RB * 4);
  unsigned short* parts = (unsigned short*)alloc(2 * arrStride * 2);
  int*   colidx  = (int*)alloc((size_t)E * 4);
  float* bufA    = (float*)alloc((size_t)N * DHID * 4);
  float* bufB    = (float*)alloc((size_t)N * DHID * 4);
  float* pbase   = (float*)alloc(((size_t)2 * G * DHID + 2 * G) * 4);
  float* pooled_su = pbase;
  float* pooled_sv = pbase + (size_t)G * DHID;
  int*   cnt_su    = (int*)(pbase + (size_t)2 * G * DHID);
  int*   cnt_sv    = cnt_su + G;
  (void)ws_size; (void)n_in; (void)out_size;

  float* pooleds[2] = {pooled_su, pooled_sv};
  int*   cnts[2]    = {cnt_su, cnt_sv};

  hipMemsetAsync(pbase, 0, ((size_t)2 * G * DHID + 2 * G) * 4, stream);

  const int TB = 256;
  const int ggrid = (N + BM - 1) / BM;
  const int agrid = (N + 3) / 4;               // wave per node
  const int PC = 25;                           // nodes per wave in pool
  const int pwaves = (N + PC - 1) / PC;
  const int pgrid = (pwaves + 3) / 4;

  for (int enc = 0; enc < 2; ++enc) {
    hist_kernel<<<dim3(SB, NCH, 2), TB, 0, stream>>>(srcs[enc], dsts[enc], parts, E, ES);
    reduce_kernel<<<RB, TB, 0, stream>>>(parts, deg_in, nsrc, ndst, sp, N, NCH);
    scan_mid<<<1, 256, 0, stream>>>(sp, rowptr + N, NB);
    scan_final<<<NB, 256, 0, stream>>>(deg_in, sp, rowptr, N);
    fillrank_kernel<<<dim3(SB, NCH), TB, 0, stream>>>(srcs[enc], dsts[enc],
                                                      parts + arrStride, rowptr,
                                                      colidx, E, ES);

    const float* in = xs[enc];
    int K = 64;
    for (int l = 0; l < 3; ++l) {
      gemm_scaled<<<ggrid, TB, 0, stream>>>(in, enc_W[enc][l], nsrc, bufB, N, K);
      agg_kernel<<<agrid, TB, 0, stream>>>(bufB, rowptr, colidx, ndst,
                                           enc_b[enc] + l * DHID, bufA, N);
      in = bufA;
      K = DHID;
    }
    pool_kernel<<<pgrid, TB, 0, stream>>>(bufA, gids[enc], pooleds[enc], cnts[enc], N, PC);
  }

  mlp_kernel<<<G, 128, 0, stream>>>(pooled_su, pooled_sv, cnt_su, cnt_sv, gfeat,
                                    mW0, mb0, mW1, mb1, mW2, mb2, (float*)d_out);
}